// Round 10
// baseline (184.297 us; speedup 1.0000x reference)
//
#include <hip/hip_runtime.h>
#include <hip/hip_bf16.h>

// MHSA: hidden[2,2048,1024], mask[2,2048] i32, W_qkv[16,1024,192] -> out[2,2048,1024]
// f32-or-bf16 inputs (per-block runtime detection in k_cvt_x). Pipeline:
// cvt X->bf16 (into d_out), QKV GEMM (global_load_lds + XOR swizzle),
// flash attention with 32x32x16 MFMA (32 q-rows/wave: halves LDS bytes/q vs
// 16x16x32 — k_attn is LDS-read-BW-bound), base-2 softmax, triple-buffered
// async K/V staging with raw s_barrier + manual vmcnt(4).

#define NH   16
#define HD   64
#define SEQ  2048
#define HID  1024
#define E3   192
#define QSCALE 0.04508422017f     // (1/32) * log2(e)
#define MBIAS  -43.2808512f       // -30 * log2(e)

typedef __attribute__((ext_vector_type(8)))  short short8;
typedef __attribute__((ext_vector_type(4)))  float f32x4;
typedef __attribute__((ext_vector_type(16))) float f32x16;
typedef unsigned short ushort_t;

#define MFMA16(a, b, c) __builtin_amdgcn_mfma_f32_16x16x32_bf16((a), (b), (c), 0, 0, 0)
#define MFMA32(a, b, c) __builtin_amdgcn_mfma_f32_32x32x16_bf16((a), (b), (c), 0, 0, 0)

#if __has_builtin(__builtin_amdgcn_exp2f)
#define EXP2(x) __builtin_amdgcn_exp2f(x)
#else
#define EXP2(x) exp2f(x)
#endif

static __device__ __forceinline__ ushort_t f2bf(float x) {
    unsigned u = __builtin_bit_cast(unsigned, x);
    unsigned r = u + 0x7fff + ((u >> 16) & 1);   // RNE
    return (ushort_t)(r >> 16);
}

static __device__ __forceinline__ unsigned pack_trunc(float hi, float lo) {
#if __has_builtin(__builtin_amdgcn_perm)
    return __builtin_amdgcn_perm(__builtin_bit_cast(unsigned, hi),
                                 __builtin_bit_cast(unsigned, lo), 0x07060302u);
#else
    return (__builtin_bit_cast(unsigned, hi) & 0xffff0000u) |
           (__builtin_bit_cast(unsigned, lo) >> 16);
#endif
}

// async global->LDS, 16B/lane; lds dest = wave-uniform base + lane*16
static __device__ __forceinline__ void load_lds16(const void* g, void* l) {
    __builtin_amdgcn_global_load_lds(
        (__attribute__((address_space(1))) void*)(g),
        (__attribute__((address_space(3))) void*)(l), 16, 0, 0);
}

// ---------------------------------------------------------------------------
// Kernel X: X (f32 or bf16) -> Xb bf16 [4096,1024] (Xb lives in d_out).
// Per-block dtype detection; block 0 publishes the flag (stream-ordered).
// ---------------------------------------------------------------------------
__global__ __launch_bounds__(256) void k_cvt_x(const void* __restrict__ Xv,
                                               ushort_t* __restrict__ Xb,
                                               int* __restrict__ flagp) {
    __shared__ int cnt;
    if (threadIdx.x == 0) cnt = 0;
    __syncthreads();
    const unsigned* X32 = (const unsigned*)Xv;
    if (threadIdx.x < 64) {
        unsigned u = X32[(size_t)blockIdx.x * 2048 + threadIdx.x * 32 + 7];
        int bexp = (u >> 7) & 0xFF;
        if (bexp >= 0x68 && bexp <= 0x90) atomicAdd(&cnt, 1);
    }
    __syncthreads();
    const int isf32 = (cnt < 32);
    if (blockIdx.x == 0 && threadIdx.x == 0) *flagp = isf32;

    const size_t base = ((size_t)blockIdx.x * 256 + threadIdx.x) * 16;
    if (isf32) {
        const float* Xf = (const float*)Xv;
        ushort_t tmp[16];
#pragma unroll
        for (int c = 0; c < 4; ++c) {
            float4 v = *(const float4*)(Xf + base + c * 4);
            tmp[c * 4 + 0] = f2bf(v.x); tmp[c * 4 + 1] = f2bf(v.y);
            tmp[c * 4 + 2] = f2bf(v.z); tmp[c * 4 + 3] = f2bf(v.w);
        }
        *(float4*)(Xb + base)     = ((const float4*)tmp)[0];
        *(float4*)(Xb + base + 8) = ((const float4*)tmp)[1];
    } else {
        const ushort_t* Xh = (const ushort_t*)Xv;
        *(float4*)(Xb + base)     = *(const float4*)(Xh + base);
        *(float4*)(Xb + base + 8) = *(const float4*)(Xh + base + 8);
    }
}

// ---------------------------------------------------------------------------
// Kernel A: W_qkv [h][D][e] (f32 or bf16) -> Wt [h*192+e][D] bf16 (3072 x 1024)
// ---------------------------------------------------------------------------
__global__ __launch_bounds__(256) void k_cvt_w(const void* __restrict__ Wv,
                                               ushort_t* __restrict__ Wt,
                                               const int* __restrict__ flagp) {
    __shared__ ushort_t tile[64][72];
    const int isf32 = *flagp;
    const int h  = blockIdx.x;
    const int dt = blockIdx.y;
    const int et = blockIdx.z;
    const int D0 = dt * 64, e0 = et * 64;
    const int t  = threadIdx.x;
#pragma unroll
    for (int r = 0; r < 2; ++r) {
        int row = r * 32 + (t >> 3);
        int col = (t & 7) * 8;
        size_t base = ((size_t)(h * HID + D0 + row)) * E3 + e0 + col;
        if (isf32) {
            const float* Wf = (const float*)Wv;
            float4 a = *(const float4*)(Wf + base);
            float4 c = *(const float4*)(Wf + base + 4);
            tile[row][col + 0] = f2bf(a.x); tile[row][col + 1] = f2bf(a.y);
            tile[row][col + 2] = f2bf(a.z); tile[row][col + 3] = f2bf(a.w);
            tile[row][col + 4] = f2bf(c.x); tile[row][col + 5] = f2bf(c.y);
            tile[row][col + 6] = f2bf(c.z); tile[row][col + 7] = f2bf(c.w);
        } else {
            *(float4*)&tile[row][col] = *(const float4*)((const ushort_t*)Wv + base);
        }
    }
    __syncthreads();
#pragma unroll
    for (int r = 0; r < 2; ++r) {
        int erow = r * 32 + (t >> 3);
        int dcol = (t & 7) * 8;
        ushort_t vals[8];
#pragma unroll
        for (int i = 0; i < 8; ++i) vals[i] = tile[dcol + i][erow];
        *(float4*)(Wt + ((size_t)(h * E3 + e0 + erow)) * HID + D0 + dcol) = *(float4*)vals;
    }
}

// ---------------------------------------------------------------------------
// Kernel B: fused QKV GEMM (verified r7 structure, unchanged).
// ---------------------------------------------------------------------------
__global__ __launch_bounds__(256) void k_qkv(const ushort_t* __restrict__ Xb,
                                             const ushort_t* __restrict__ Wt,
                                             ushort_t* __restrict__ Qb,
                                             ushort_t* __restrict__ Kb,
                                             ushort_t* __restrict__ Vtb) {
    __shared__ __align__(16) ushort_t smem[2 * 128 * 64];
    ushort_t* Xl = smem;
    ushort_t* Wl = smem + 128 * 64;

    const int e0 = blockIdx.x * 128;
    const int m0 = blockIdx.y * 128;
    const int b  = m0 >> 11;
    const int n0 = m0 & 2047;
    const int t = threadIdx.x;
    const int w = t >> 6, lane = t & 63, l15 = lane & 15, quad = lane >> 4;
    const int wrow0 = (w & 1) * 64, wcol0 = (w >> 1) * 64;
    const int srow = lane >> 3;
    const int scb  = (lane & 7) ^ srow;

    f32x4 acc[4][4];
#pragma unroll
    for (int i = 0; i < 4; ++i)
#pragma unroll
        for (int j = 0; j < 4; ++j) acc[i][j] = (f32x4){0.f, 0.f, 0.f, 0.f};

    for (int k0 = 0; k0 < HID; k0 += 64) {
        __syncthreads();
#pragma unroll
        for (int cc = 0; cc < 4; ++cc) {
            const int ch  = w * 4 + cc;
            const int row = ch * 8 + srow;
            load_lds16(Xb + (size_t)(m0 + row) * HID + k0 + scb * 8, &Xl[ch * 512]);
            load_lds16(Wt + (size_t)(e0 + row) * HID + k0 + scb * 8, &Wl[ch * 512]);
        }
        __syncthreads();
#pragma unroll
        for (int kh = 0; kh < 2; ++kh) {
            short8 af[4], bfm[4];
#pragma unroll
            for (int i = 0; i < 4; ++i) {
                const int r = wrow0 + i * 16 + l15;
                af[i] = *(const short8*)&Xl[r * 64 + ((kh * 4 + quad) ^ (r & 7)) * 8];
            }
#pragma unroll
            for (int j = 0; j < 4; ++j) {
                const int r = wcol0 + j * 16 + l15;
                bfm[j] = *(const short8*)&Wl[r * 64 + ((kh * 4 + quad) ^ (r & 7)) * 8];
            }
#pragma unroll
            for (int i = 0; i < 4; ++i)
#pragma unroll
                for (int j = 0; j < 4; ++j)
                    acc[i][j] = MFMA16(af[i], bfm[j], acc[i][j]);
        }
    }

    ushort_t* Vbuf = smem;
    __syncthreads();
#pragma unroll
    for (int i = 0; i < 4; ++i) {
#pragma unroll
        for (int j = 0; j < 4; ++j) {
            const int E0v = e0 + wcol0 + j * 16;
            const int hh  = E0v / 192;
            const int r0  = E0v - hh * 192;
            const int bh  = b * NH + hh;
            const int nb  = n0 + wrow0 + i * 16 + quad * 4;
            if (r0 < 64) {
                const int e = r0 + l15;
#pragma unroll
                for (int reg = 0; reg < 4; ++reg)
                    Qb[((size_t)bh * SEQ + nb + reg) * HD + e] = f2bf(acc[i][j][reg] * QSCALE);
            } else if (r0 < 128) {
                const int e = r0 - 64 + l15;
#pragma unroll
                for (int reg = 0; reg < 4; ++reg)
                    Kb[((size_t)bh * SEQ + nb + reg) * HD + e] = f2bf(acc[i][j][reg]);
            } else {
                const int d  = r0 - 128 + l15;
                const int nl = wrow0 + i * 16 + quad * 4;
#pragma unroll
                for (int reg = 0; reg < 4; ++reg)
                    Vbuf[d * 136 + nl + reg] = f2bf(acc[i][j][reg]);
            }
        }
    }
    const int m3 = blockIdx.x % 3;
    if (m3 != 0) {
        __syncthreads();
        const int hv  = (e0 + ((m3 == 1) ? 0 : 64)) / 192;
        const int bhv = b * NH + hv;
        const int dr = t >> 2, part = t & 3;
        size_t dst = ((size_t)bhv * HD + dr) * SEQ + n0 + part * 32;
#pragma unroll
        for (int c = 0; c < 4; ++c) {
            float4 v = *(const float4*)&Vbuf[dr * 136 + part * 32 + c * 8];
            *(float4*)(Vtb + dst + c * 8) = v;
        }
    }
}

// ---------------------------------------------------------------------------
// Kernel C: flash attention, 32x32x16 MFMA, 32 q-rows/wave, 4 waves = 128 q.
// S^T = K*Q^T: A=K[key][d] frags (lane: row=lane&31, k=8*(lane>>5)+j),
// B=Q (registers). C/D: col=q=lane&31, row=(reg&3)+8*(reg>>2)+4*(lane>>5).
// l is per-lane scalar (one q per lane). P stored as P[q][key] (stride 72):
// b64 writes per reg-quad, b128 B-frag reads. PV: O^T = V^T * P^T.
// Triple-buffered DMA staging, raw s_barrier + vmcnt(4).
// ---------------------------------------------------------------------------
__global__ __launch_bounds__(256) void k_attn(const ushort_t* __restrict__ Qb,
                                              const ushort_t* __restrict__ Kb,
                                              const ushort_t* __restrict__ Vtb,
                                              const int* __restrict__ mask,
                                              void* __restrict__ outv,
                                              const int* __restrict__ flagp) {
    __shared__ __align__(16) char smem_raw[75776];
    // bufs: 3 x 16384 B (K 8192 | V 8192); Pl at 49152 (128*72*2=18432); bias at 67584
    ushort_t* Pl    = (ushort_t*)(smem_raw + 49152);
    float*    biasl = (float*)(smem_raw + 67584);

    const int isf32 = *flagp;
    const int q0 = blockIdx.x * 128;
    const int bh = blockIdx.y;
    const int b  = bh >> 4, h = bh & 15;
    const int t  = threadIdx.x;
    const int w  = t >> 6, lane = t & 63;
    const int l31 = lane & 31, half = lane >> 5;
    const int srow = lane >> 3;
    const int scb  = (lane & 7) ^ srow;
    const int prow = w * 32 + l31;              // this lane's q (block-local)

    const f32x16 zero16 = {0.f,0.f,0.f,0.f,0.f,0.f,0.f,0.f,
                           0.f,0.f,0.f,0.f,0.f,0.f,0.f,0.f};

    // issue pair(0)->buf0, pair(1)->buf1 (4 loads each wave per tile? 2K+2V)
#pragma unroll
    for (int tj = 0; tj < 2; ++tj) {
        ushort_t* kb = (ushort_t*)(smem_raw + tj * 16384);
        ushort_t* vb = kb + 4096;
#pragma unroll
        for (int c = 0; c < 2; ++c) {
            const int ch  = w * 2 + c;          // 0..7
            const int row = ch * 8 + srow;      // 0..63
            load_lds16(Kb  + ((size_t)bh * SEQ + tj * 64 + row) * HD + scb * 8, &kb[ch * 512]);
            load_lds16(Vtb + ((size_t)bh * HD + row) * SEQ + tj * 64 + scb * 8, &vb[ch * 512]);
        }
    }

    int lm = 0;
    for (int i = t; i < SEQ; i += 256) {
        int mv = mask[b * SEQ + i];
        biasl[i] = mv ? 0.0f : MBIAS;
        lm |= (mv == 0);
    }
    // Q fragments: Q[q = q0+prow][d = s*16 + half*8 + j], s=0..3
    short8 qa[4];
#pragma unroll
    for (int s = 0; s < 4; ++s)
        qa[s] = *(const short8*)(Qb + ((size_t)bh * SEQ + q0 + prow) * HD + s * 16 + half * 8);

    const int use_bias = __syncthreads_or(lm);  // full drain: tiles 0,1 ready

    f32x16 o[2];
    o[0] = zero16; o[1] = zero16;
    float l_r = 0.f;

    for (int j0 = 0; j0 < SEQ; j0 += 64) {
        const int idx = (j0 >> 6) % 3;
        if (j0 + 64 < SEQ) { asm volatile("s_waitcnt vmcnt(4)" ::: "memory"); }
        else               { asm volatile("s_waitcnt vmcnt(0)" ::: "memory"); }
        __builtin_amdgcn_s_barrier();
        asm volatile("" ::: "memory");
        if (j0 + 128 < SEQ) {                   // stage tile j+2
            ushort_t* kb = (ushort_t*)(smem_raw + ((idx + 2) % 3) * 16384);
            ushort_t* vb = kb + 4096;
#pragma unroll
            for (int c = 0; c < 2; ++c) {
                const int ch  = w * 2 + c;
                const int row = ch * 8 + srow;
                load_lds16(Kb  + ((size_t)bh * SEQ + j0 + 128 + row) * HD + scb * 8, &kb[ch * 512]);
                load_lds16(Vtb + ((size_t)bh * HD + row) * SEQ + j0 + 128 + scb * 8, &vb[ch * 512]);
            }
        }
        ushort_t* kb = (ushort_t*)(smem_raw + idx * 16384);
        ushort_t* vb = kb + 4096;

        // ---- S^T[key][q]: 2 key-tiles x 4 d-steps of 32x32x16 ----
        f32x16 st[2];
#pragma unroll
        for (int kt = 0; kt < 2; ++kt) {
            const int rk = kt * 32 + l31;
            st[kt] = zero16;
#pragma unroll
            for (int s = 0; s < 4; ++s) {
                short8 ka = *(const short8*)&kb[rk * 64 + ((2 * s + half) ^ (rk & 7)) * 8];
                st[kt] = MFMA32(ka, qa[s], st[kt]);
            }
        }
        if (use_bias) {
#pragma unroll
            for (int kt = 0; kt < 2; ++kt)
#pragma unroll
                for (int g = 0; g < 4; ++g) {
                    float4 bj = *(const float4*)&biasl[j0 + kt * 32 + g * 8 + 4 * half];
#pragma unroll
                    for (int i = 0; i < 4; ++i)
                        st[kt][g * 4 + i] += ((const float*)&bj)[i];
                }
        }

        // ---- p = 2^s; per-lane l (one q per lane); P[q][key] b64 stores ----
#pragma unroll
        for (int kt = 0; kt < 2; ++kt) {
            float p[16];
#pragma unroll
            for (int r = 0; r < 16; ++r) { p[r] = EXP2(st[kt][r]); l_r += p[r]; }
#pragma unroll
            for (int g = 0; g < 4; ++g) {
                uint2 u;
                u.x = pack_trunc(p[4 * g + 1], p[4 * g + 0]);
                u.y = pack_trunc(p[4 * g + 3], p[4 * g + 2]);
                *(uint2*)&Pl[prow * 72 + kt * 32 + g * 8 + 4 * half] = u;
            }
        }
        // P rows are wave-private (q bands disjoint): no barrier.
        short8 pb[4];
#pragma unroll
        for (int s = 0; s < 4; ++s)
            pb[s] = *(const short8*)&Pl[prow * 72 + s * 16 + half * 8];

        // ---- O^T[d][q] += V^T * P^T: 2 d-tiles x 4 key-steps ----
#pragma unroll
        for (int dt = 0; dt < 2; ++dt) {
            const int rv = dt * 32 + l31;
#pragma unroll
            for (int s = 0; s < 4; ++s) {
                short8 va = *(const short8*)&vb[rv * 64 + ((2 * s + half) ^ (rv & 7)) * 8];
                o[dt] = MFMA32(va, pb[s], o[dt]);
            }
        }
    }

    // ---- l: lanes L, L+32 share q ----
    l_r += __shfl_xor(l_r, 32);
    const float rinv = 1.0f / l_r;

    __syncthreads();
    const int r = t >> 1, part = t & 1;         // r 0..127, part: 32-d half
    if (!isf32) {
        ushort_t* Ol = (ushort_t*)smem_raw;     // [q_local][d] stride 72
#pragma unroll
        for (int dt = 0; dt < 2; ++dt)
#pragma unroll
            for (int g = 0; g < 4; ++g) {
                uint2 u;
                u.x = (unsigned)f2bf(o[dt][4 * g + 0] * rinv) |
                      ((unsigned)f2bf(o[dt][4 * g + 1] * rinv) << 16);
                u.y = (unsigned)f2bf(o[dt][4 * g + 2] * rinv) |
                      ((unsigned)f2bf(o[dt][4 * g + 3] * rinv) << 16);
                *(uint2*)&Ol[prow * 72 + dt * 32 + g * 8 + 4 * half] = u;
            }
        __syncthreads();
        ushort_t* outp = (ushort_t*)outv;
        size_t dst = ((size_t)b * SEQ + q0 + r) * HID + h * HD + part * 32;
#pragma unroll
        for (int c = 0; c < 4; ++c) {
            float4 v = *(const float4*)&Ol[r * 72 + part * 32 + c * 8];
            *(float4*)(outp + dst + c * 8) = v;
        }
    } else {
        float* Olf = (float*)smem_raw;          // [q_local][d] stride 68
#pragma unroll
        for (int dt = 0; dt < 2; ++dt)
#pragma unroll
            for (int g = 0; g < 4; ++g) {
                float2 v0 = {o[dt][4 * g + 0] * rinv, o[dt][4 * g + 1] * rinv};
                float2 v1 = {o[dt][4 * g + 2] * rinv, o[dt][4 * g + 3] * rinv};
                *(float2*)&Olf[prow * 68 + dt * 32 + g * 8 + 4 * half]     = v0;
                *(float2*)&Olf[prow * 68 + dt * 32 + g * 8 + 4 * half + 2] = v1;
            }
        __syncthreads();
        float* outp = (float*)outv;
        size_t dst = ((size_t)b * SEQ + q0 + r) * HID + h * HD + part * 32;
#pragma unroll
        for (int c = 0; c < 8; ++c) {
            float4 v = *(const float4*)&Olf[r * 68 + part * 32 + c * 4];
            *(float4*)(outp + dst + c * 4) = v;
        }
    }
}

// ---------------------------------------------------------------------------
extern "C" void kernel_launch(void* const* d_in, const int* in_sizes, int n_in,
                              void* d_out, int out_size, void* d_ws, size_t ws_size,
                              hipStream_t stream) {
    const void* X    = d_in[0];                 // hidden_states [2,2048,1024] f32 or bf16
    const int*  mask = (const int*)d_in[1];     // attention_mask i32 [2,2048]
    const void* W    = d_in[2];                 // W_qkv [16,1024,192] f32 or bf16

    char* ws = (char*)d_ws;
    // ws: Q 8MB | K 8MB | Vt 8MB | Wt 6MB | flag.  Xb (bf16 X) lives in d_out.
    ushort_t* Qb    = (ushort_t*)(ws);
    ushort_t* Kb    = (ushort_t*)(ws + 8388608);
    ushort_t* Vtb   = (ushort_t*)(ws + 16777216);
    ushort_t* Wtb   = (ushort_t*)(ws + 25165824);
    int*      flagp = (int*)(ws + 31457280);
    ushort_t* Xb    = (ushort_t*)d_out;

    k_cvt_x<<<1024, 256, 0, stream>>>(X, Xb, flagp);
    k_cvt_w<<<dim3(16, 16, 3), 256, 0, stream>>>(W, Wtb, flagp);
    k_qkv<<<dim3(24, 32), 256, 0, stream>>>(Xb, Wtb, Qb, Kb, Vtb);
    k_attn<<<dim3(16, 32), 256, 0, stream>>>(Qb, Kb, Vtb, mask, d_out, flagp);
}

// Round 11
// 180.783 us; speedup vs baseline: 1.0194x; 1.0194x over previous
//
#include <hip/hip_runtime.h>
#include <hip/hip_bf16.h>

// MHSA: hidden[2,2048,1024], mask[2,2048] i32, W_qkv[16,1024,192] -> out[2,2048,1024]
// f32-or-bf16 inputs (per-block runtime detection in k_cvt_x). Pipeline:
// cvt X->bf16 (into d_out), QKV GEMM (global_load_lds + XOR swizzle),
// flash attention: 32x32x16 MFMA, 512-thread blocks, TWO key-split wave groups
// (waves 0-3: keys 0-1023, waves 4-7: keys 1024-2047, same 128 q) -> 16
// waves/CU with the 32x32 operand economy. Fixed-max base-2 softmax => the
// split combine is a plain add: O=(O0+O1)/(l0+l1). Triple-buffered DMA K/V
// staging per group, raw s_barrier + vmcnt(2).

#define NH   16
#define HD   64
#define SEQ  2048
#define HID  1024
#define E3   192
#define QSCALE 0.04508422017f     // (1/32) * log2(e)
#define MBIAS  -43.2808512f       // -30 * log2(e)

typedef __attribute__((ext_vector_type(8)))  short short8;
typedef __attribute__((ext_vector_type(4)))  float f32x4;
typedef __attribute__((ext_vector_type(16))) float f32x16;
typedef unsigned short ushort_t;

#define MFMA16(a, b, c) __builtin_amdgcn_mfma_f32_16x16x32_bf16((a), (b), (c), 0, 0, 0)
#define MFMA32(a, b, c) __builtin_amdgcn_mfma_f32_32x32x16_bf16((a), (b), (c), 0, 0, 0)

#if __has_builtin(__builtin_amdgcn_exp2f)
#define EXP2(x) __builtin_amdgcn_exp2f(x)
#else
#define EXP2(x) exp2f(x)
#endif

static __device__ __forceinline__ ushort_t f2bf(float x) {
    unsigned u = __builtin_bit_cast(unsigned, x);
    unsigned r = u + 0x7fff + ((u >> 16) & 1);   // RNE
    return (ushort_t)(r >> 16);
}

static __device__ __forceinline__ unsigned pack_trunc(float hi, float lo) {
#if __has_builtin(__builtin_amdgcn_perm)
    return __builtin_amdgcn_perm(__builtin_bit_cast(unsigned, hi),
                                 __builtin_bit_cast(unsigned, lo), 0x07060302u);
#else
    return (__builtin_bit_cast(unsigned, hi) & 0xffff0000u) |
           (__builtin_bit_cast(unsigned, lo) >> 16);
#endif
}

// async global->LDS, 16B/lane; lds dest = wave-uniform base + lane*16
static __device__ __forceinline__ void load_lds16(const void* g, void* l) {
    __builtin_amdgcn_global_load_lds(
        (__attribute__((address_space(1))) void*)(g),
        (__attribute__((address_space(3))) void*)(l), 16, 0, 0);
}

// ---------------------------------------------------------------------------
// Kernel X: X (f32 or bf16) -> Xb bf16 [4096,1024] (Xb lives in d_out).
// ---------------------------------------------------------------------------
__global__ __launch_bounds__(256) void k_cvt_x(const void* __restrict__ Xv,
                                               ushort_t* __restrict__ Xb,
                                               int* __restrict__ flagp) {
    __shared__ int cnt;
    if (threadIdx.x == 0) cnt = 0;
    __syncthreads();
    const unsigned* X32 = (const unsigned*)Xv;
    if (threadIdx.x < 64) {
        unsigned u = X32[(size_t)blockIdx.x * 2048 + threadIdx.x * 32 + 7];
        int bexp = (u >> 7) & 0xFF;
        if (bexp >= 0x68 && bexp <= 0x90) atomicAdd(&cnt, 1);
    }
    __syncthreads();
    const int isf32 = (cnt < 32);
    if (blockIdx.x == 0 && threadIdx.x == 0) *flagp = isf32;

    const size_t base = ((size_t)blockIdx.x * 256 + threadIdx.x) * 16;
    if (isf32) {
        const float* Xf = (const float*)Xv;
        ushort_t tmp[16];
#pragma unroll
        for (int c = 0; c < 4; ++c) {
            float4 v = *(const float4*)(Xf + base + c * 4);
            tmp[c * 4 + 0] = f2bf(v.x); tmp[c * 4 + 1] = f2bf(v.y);
            tmp[c * 4 + 2] = f2bf(v.z); tmp[c * 4 + 3] = f2bf(v.w);
        }
        *(float4*)(Xb + base)     = ((const float4*)tmp)[0];
        *(float4*)(Xb + base + 8) = ((const float4*)tmp)[1];
    } else {
        const ushort_t* Xh = (const ushort_t*)Xv;
        *(float4*)(Xb + base)     = *(const float4*)(Xh + base);
        *(float4*)(Xb + base + 8) = *(const float4*)(Xh + base + 8);
    }
}

// ---------------------------------------------------------------------------
// Kernel A: W_qkv [h][D][e] (f32 or bf16) -> Wt [h*192+e][D] bf16 (3072 x 1024)
// ---------------------------------------------------------------------------
__global__ __launch_bounds__(256) void k_cvt_w(const void* __restrict__ Wv,
                                               ushort_t* __restrict__ Wt,
                                               const int* __restrict__ flagp) {
    __shared__ ushort_t tile[64][72];
    const int isf32 = *flagp;
    const int h  = blockIdx.x;
    const int dt = blockIdx.y;
    const int et = blockIdx.z;
    const int D0 = dt * 64, e0 = et * 64;
    const int t  = threadIdx.x;
#pragma unroll
    for (int r = 0; r < 2; ++r) {
        int row = r * 32 + (t >> 3);
        int col = (t & 7) * 8;
        size_t base = ((size_t)(h * HID + D0 + row)) * E3 + e0 + col;
        if (isf32) {
            const float* Wf = (const float*)Wv;
            float4 a = *(const float4*)(Wf + base);
            float4 c = *(const float4*)(Wf + base + 4);
            tile[row][col + 0] = f2bf(a.x); tile[row][col + 1] = f2bf(a.y);
            tile[row][col + 2] = f2bf(a.z); tile[row][col + 3] = f2bf(a.w);
            tile[row][col + 4] = f2bf(c.x); tile[row][col + 5] = f2bf(c.y);
            tile[row][col + 6] = f2bf(c.z); tile[row][col + 7] = f2bf(c.w);
        } else {
            *(float4*)&tile[row][col] = *(const float4*)((const ushort_t*)Wv + base);
        }
    }
    __syncthreads();
#pragma unroll
    for (int r = 0; r < 2; ++r) {
        int erow = r * 32 + (t >> 3);
        int dcol = (t & 7) * 8;
        ushort_t vals[8];
#pragma unroll
        for (int i = 0; i < 8; ++i) vals[i] = tile[dcol + i][erow];
        *(float4*)(Wt + ((size_t)(h * E3 + e0 + erow)) * HID + D0 + dcol) = *(float4*)vals;
    }
}

// ---------------------------------------------------------------------------
// Kernel B: fused QKV GEMM (verified r7 structure, unchanged).
// ---------------------------------------------------------------------------
__global__ __launch_bounds__(256) void k_qkv(const ushort_t* __restrict__ Xb,
                                             const ushort_t* __restrict__ Wt,
                                             ushort_t* __restrict__ Qb,
                                             ushort_t* __restrict__ Kb,
                                             ushort_t* __restrict__ Vtb) {
    __shared__ __align__(16) ushort_t smem[2 * 128 * 64];
    ushort_t* Xl = smem;
    ushort_t* Wl = smem + 128 * 64;

    const int e0 = blockIdx.x * 128;
    const int m0 = blockIdx.y * 128;
    const int b  = m0 >> 11;
    const int n0 = m0 & 2047;
    const int t = threadIdx.x;
    const int w = t >> 6, lane = t & 63, l15 = lane & 15, quad = lane >> 4;
    const int wrow0 = (w & 1) * 64, wcol0 = (w >> 1) * 64;
    const int srow = lane >> 3;
    const int scb  = (lane & 7) ^ srow;

    f32x4 acc[4][4];
#pragma unroll
    for (int i = 0; i < 4; ++i)
#pragma unroll
        for (int j = 0; j < 4; ++j) acc[i][j] = (f32x4){0.f, 0.f, 0.f, 0.f};

    for (int k0 = 0; k0 < HID; k0 += 64) {
        __syncthreads();
#pragma unroll
        for (int cc = 0; cc < 4; ++cc) {
            const int ch  = w * 4 + cc;
            const int row = ch * 8 + srow;
            load_lds16(Xb + (size_t)(m0 + row) * HID + k0 + scb * 8, &Xl[ch * 512]);
            load_lds16(Wt + (size_t)(e0 + row) * HID + k0 + scb * 8, &Wl[ch * 512]);
        }
        __syncthreads();
#pragma unroll
        for (int kh = 0; kh < 2; ++kh) {
            short8 af[4], bfm[4];
#pragma unroll
            for (int i = 0; i < 4; ++i) {
                const int r = wrow0 + i * 16 + l15;
                af[i] = *(const short8*)&Xl[r * 64 + ((kh * 4 + quad) ^ (r & 7)) * 8];
            }
#pragma unroll
            for (int j = 0; j < 4; ++j) {
                const int r = wcol0 + j * 16 + l15;
                bfm[j] = *(const short8*)&Wl[r * 64 + ((kh * 4 + quad) ^ (r & 7)) * 8];
            }
#pragma unroll
            for (int i = 0; i < 4; ++i)
#pragma unroll
                for (int j = 0; j < 4; ++j)
                    acc[i][j] = MFMA16(af[i], bfm[j], acc[i][j]);
        }
    }

    ushort_t* Vbuf = smem;
    __syncthreads();
#pragma unroll
    for (int i = 0; i < 4; ++i) {
#pragma unroll
        for (int j = 0; j < 4; ++j) {
            const int E0v = e0 + wcol0 + j * 16;
            const int hh  = E0v / 192;
            const int r0  = E0v - hh * 192;
            const int bh  = b * NH + hh;
            const int nb  = n0 + wrow0 + i * 16 + quad * 4;
            if (r0 < 64) {
                const int e = r0 + l15;
#pragma unroll
                for (int reg = 0; reg < 4; ++reg)
                    Qb[((size_t)bh * SEQ + nb + reg) * HD + e] = f2bf(acc[i][j][reg] * QSCALE);
            } else if (r0 < 128) {
                const int e = r0 - 64 + l15;
#pragma unroll
                for (int reg = 0; reg < 4; ++reg)
                    Kb[((size_t)bh * SEQ + nb + reg) * HD + e] = f2bf(acc[i][j][reg]);
            } else {
                const int d  = r0 - 128 + l15;
                const int nl = wrow0 + i * 16 + quad * 4;
#pragma unroll
                for (int reg = 0; reg < 4; ++reg)
                    Vbuf[d * 136 + nl + reg] = f2bf(acc[i][j][reg]);
            }
        }
    }
    const int m3 = blockIdx.x % 3;
    if (m3 != 0) {
        __syncthreads();
        const int hv  = (e0 + ((m3 == 1) ? 0 : 64)) / 192;
        const int bhv = b * NH + hv;
        const int dr = t >> 2, part = t & 3;
        size_t dst = ((size_t)bhv * HD + dr) * SEQ + n0 + part * 32;
#pragma unroll
        for (int c = 0; c < 4; ++c) {
            float4 v = *(const float4*)&Vbuf[dr * 136 + part * 32 + c * 8];
            *(float4*)(Vtb + dst + c * 8) = v;
        }
    }
}

// ---------------------------------------------------------------------------
// Kernel C: flash attention, 32x32x16 MFMA, 512 threads = 8 waves in 2 key-
// split groups (group g: keys g*1024..g*1024+1023), 128 q-rows/block.
// Per group: 32 iters of 32-key tiles, triple-buffered DMA staging (1 K + 1 V
// load/wave/tile), raw s_barrier + vmcnt(2). Combine: O=(O0+O1)/(l0+l1).
// LDS map: [0,49152) KV bufs (grp0: 3x8192 @0, grp1: @24576; tile = K 4096 |
// V 4096); [49152,69632) Pl (grp stride 10240); [69632,77824) bias f32.
// ---------------------------------------------------------------------------
__global__ __launch_bounds__(512) void k_attn(const ushort_t* __restrict__ Qb,
                                              const ushort_t* __restrict__ Kb,
                                              const ushort_t* __restrict__ Vtb,
                                              const int* __restrict__ mask,
                                              void* __restrict__ outv,
                                              const int* __restrict__ flagp) {
    __shared__ __align__(16) char smem_raw[77824];
    float* biasl = (float*)(smem_raw + 69632);      // 2048 f32 (base-2 units)

    const int isf32 = *flagp;
    const int q0 = blockIdx.x * 128;
    const int bh = blockIdx.y;
    const int b  = bh >> 4, h = bh & 15;
    const int t  = threadIdx.x;
    const int w  = t >> 6, lane = t & 63;
    const int l31 = lane & 31, half = lane >> 5;
    const int g   = w >> 2, wg = w & 3;             // group, wave-in-group
    const int prow = wg * 32 + l31;                 // lane's q (block-local)
    const int kbase = g * 1024;                     // group's key range start
    char* bufs = smem_raw + g * 24576;              // group's 3 KV buffers
    ushort_t* Pl = (ushort_t*)(smem_raw + 49152 + g * 10240); // P[q][key] stride 40

    // K staging: lane covers row wg*8+(L>>3), chunk (L&7)^(row&7)
    const int ksr = lane >> 3, kcb = (lane & 7) ^ ksr;
    // V staging: lane covers d = wg*16+(L>>2), chunk (L&3)^(d&3)
    const int vdr = lane >> 2, vcb = (lane & 3) ^ (vdr & 3);

    const f32x16 zero16 = {0.f,0.f,0.f,0.f,0.f,0.f,0.f,0.f,
                           0.f,0.f,0.f,0.f,0.f,0.f,0.f,0.f};

    // preload tiles 0,1 (drained by the setup barrier)
#pragma unroll
    for (int tj = 0; tj < 2; ++tj) {
        ushort_t* kb = (ushort_t*)(bufs + tj * 8192);
        ushort_t* vb = kb + 2048;
        const int j0g = kbase + tj * 32;
        load_lds16(Kb  + ((size_t)bh * SEQ + j0g + wg * 8 + ksr) * HD + kcb * 8, &kb[wg * 512]);
        load_lds16(Vtb + ((size_t)bh * HD + wg * 16 + vdr) * SEQ + j0g + vcb * 8, &vb[wg * 512]);
    }

    int lm = 0;
    for (int i = t; i < SEQ; i += 512) {
        int mv = mask[b * SEQ + i];
        biasl[i] = mv ? 0.0f : MBIAS;
        lm |= (mv == 0);
    }
    // Q fragments: Q[q0+prow][d = s*16 + half*8 + j]
    short8 qa[4];
#pragma unroll
    for (int s = 0; s < 4; ++s)
        qa[s] = *(const short8*)(Qb + ((size_t)bh * SEQ + q0 + prow) * HD + s * 16 + half * 8);

    const int use_bias = __syncthreads_or(lm);      // full drain: tiles 0,1 ready

    f32x16 o[2];
    o[0] = zero16; o[1] = zero16;
    float l_r = 0.f;

    for (int it = 0; it < 32; ++it) {
        const int idx = it % 3;
        if (it < 31) { asm volatile("s_waitcnt vmcnt(2)" ::: "memory"); }
        else         { asm volatile("s_waitcnt vmcnt(0)" ::: "memory"); }
        __builtin_amdgcn_s_barrier();
        asm volatile("" ::: "memory");
        if (it < 30) {                              // stage tile it+2
            ushort_t* kb = (ushort_t*)(bufs + ((idx + 2) % 3) * 8192);
            ushort_t* vb = kb + 2048;
            const int j0g = kbase + (it + 2) * 32;
            load_lds16(Kb  + ((size_t)bh * SEQ + j0g + wg * 8 + ksr) * HD + kcb * 8, &kb[wg * 512]);
            load_lds16(Vtb + ((size_t)bh * HD + wg * 16 + vdr) * SEQ + j0g + vcb * 8, &vb[wg * 512]);
        }
        ushort_t* kb = (ushort_t*)(bufs + idx * 8192);
        ushort_t* vb = kb + 2048;
        const int j0g = kbase + it * 32;

        // ---- S^T[key][q]: one 32-key tile, 4 d-steps ----
        f32x16 st = zero16;
#pragma unroll
        for (int s = 0; s < 4; ++s) {
            short8 ka = *(const short8*)&kb[l31 * 64 + ((2 * s + half) ^ (l31 & 7)) * 8];
            st = MFMA32(ka, qa[s], st);
        }
        if (use_bias) {
#pragma unroll
            for (int g4 = 0; g4 < 4; ++g4) {
                float4 bj = *(const float4*)&biasl[j0g + g4 * 8 + 4 * half];
#pragma unroll
                for (int i = 0; i < 4; ++i)
                    st[g4 * 4 + i] += ((const float*)&bj)[i];
            }
        }

        // ---- p = 2^s; per-lane l; P[q][key] b64 stores ----
        float p[16];
#pragma unroll
        for (int r = 0; r < 16; ++r) { p[r] = EXP2(st[r]); l_r += p[r]; }
#pragma unroll
        for (int g4 = 0; g4 < 4; ++g4) {
            uint2 u;
            u.x = pack_trunc(p[4 * g4 + 1], p[4 * g4 + 0]);
            u.y = pack_trunc(p[4 * g4 + 3], p[4 * g4 + 2]);
            *(uint2*)&Pl[prow * 40 + g4 * 8 + 4 * half] = u;
        }
        // P rows wave-private: no barrier.
        short8 pb[2];
#pragma unroll
        for (int s = 0; s < 2; ++s)
            pb[s] = *(const short8*)&Pl[prow * 40 + s * 16 + half * 8];

        // ---- O^T[d][q] += V^T * P^T: 2 d-tiles x 2 key-steps ----
#pragma unroll
        for (int dt = 0; dt < 2; ++dt) {
            const int rv = dt * 32 + l31;
#pragma unroll
            for (int s = 0; s < 2; ++s) {
                short8 va = *(const short8*)&vb[rv * 32 + ((2 * s + half) ^ (rv & 3)) * 8];
                o[dt] = MFMA32(va, pb[s], o[dt]);
            }
        }
    }

    // ---- per-lane l over this group's keys: lanes L, L+32 share q ----
    l_r += __shfl_xor(l_r, 32);

    // ---- combine groups: group1 -> LDS, group0 adds & normalizes ----
    float* Obuf = (float*)smem_raw;                 // [128][68] f32 (34816 B)
    float* lbuf = (float*)(smem_raw + 73728);       // 128 f32
    __syncthreads();
    if (g == 1) {
#pragma unroll
        for (int dt = 0; dt < 2; ++dt)
#pragma unroll
            for (int g4 = 0; g4 < 4; ++g4) {
                float4 v = {o[dt][4 * g4 + 0], o[dt][4 * g4 + 1],
                            o[dt][4 * g4 + 2], o[dt][4 * g4 + 3]};
                *(float4*)&Obuf[prow * 68 + dt * 32 + g4 * 8 + 4 * half] = v;
            }
        if (half == 0) lbuf[prow] = l_r;
    }
    __syncthreads();
    if (g == 0) {
        const float rinv = 1.0f / (l_r + lbuf[prow]);
        if (!isf32) {
            ushort_t* Ol = (ushort_t*)(smem_raw + 36864);   // [q][d] stride 72 bf16
#pragma unroll
            for (int dt = 0; dt < 2; ++dt)
#pragma unroll
                for (int g4 = 0; g4 < 4; ++g4) {
                    float4 v = *(const float4*)&Obuf[prow * 68 + dt * 32 + g4 * 8 + 4 * half];
                    uint2 u;
                    u.x = (unsigned)f2bf((o[dt][4 * g4 + 0] + v.x) * rinv) |
                          ((unsigned)f2bf((o[dt][4 * g4 + 1] + v.y) * rinv) << 16);
                    u.y = (unsigned)f2bf((o[dt][4 * g4 + 2] + v.z) * rinv) |
                          ((unsigned)f2bf((o[dt][4 * g4 + 3] + v.w) * rinv) << 16);
                    *(uint2*)&Ol[prow * 72 + dt * 32 + g4 * 8 + 4 * half] = u;
                }
        } else {
            float* Olf = (float*)(smem_raw + 36864);        // [q][d] stride 68 f32
#pragma unroll
            for (int dt = 0; dt < 2; ++dt)
#pragma unroll
                for (int g4 = 0; g4 < 4; ++g4) {
                    float4 v = *(const float4*)&Obuf[prow * 68 + dt * 32 + g4 * 8 + 4 * half];
                    float4 r;
                    r.x = (o[dt][4 * g4 + 0] + v.x) * rinv;
                    r.y = (o[dt][4 * g4 + 1] + v.y) * rinv;
                    r.z = (o[dt][4 * g4 + 2] + v.z) * rinv;
                    r.w = (o[dt][4 * g4 + 3] + v.w) * rinv;
                    *(float4*)&Olf[prow * 68 + dt * 32 + g4 * 8 + 4 * half] = r;
                }
        }
    }
    __syncthreads();
    const int r = t >> 2, part = t & 3;             // r 0..127, 16-elem quarters
    if (!isf32) {
        ushort_t* Ol = (ushort_t*)(smem_raw + 36864);
        ushort_t* outp = (ushort_t*)outv;
        size_t dst = ((size_t)b * SEQ + q0 + r) * HID + h * HD + part * 16;
        float4 v0 = *(const float4*)&Ol[r * 72 + part * 16];
        float4 v1 = *(const float4*)&Ol[r * 72 + part * 16 + 8];
        *(float4*)(outp + dst)     = v0;
        *(float4*)(outp + dst + 8) = v1;
    } else {
        float* Olf = (float*)(smem_raw + 36864);
        float* outp = (float*)outv;
        size_t dst = ((size_t)b * SEQ + q0 + r) * HID + h * HD + part * 16;
#pragma unroll
        for (int c = 0; c < 4; ++c) {
            float4 v = *(const float4*)&Olf[r * 68 + part * 16 + c * 4];
            *(float4*)(outp + dst + c * 4) = v;
        }
    }
}

// ---------------------------------------------------------------------------
extern "C" void kernel_launch(void* const* d_in, const int* in_sizes, int n_in,
                              void* d_out, int out_size, void* d_ws, size_t ws_size,
                              hipStream_t stream) {
    const void* X    = d_in[0];                 // hidden_states [2,2048,1024] f32 or bf16
    const int*  mask = (const int*)d_in[1];     // attention_mask i32 [2,2048]
    const void* W    = d_in[2];                 // W_qkv [16,1024,192] f32 or bf16

    char* ws = (char*)d_ws;
    // ws: Q 8MB | K 8MB | Vt 8MB | Wt 6MB | flag.  Xb (bf16 X) lives in d_out.
    ushort_t* Qb    = (ushort_t*)(ws);
    ushort_t* Kb    = (ushort_t*)(ws + 8388608);
    ushort_t* Vtb   = (ushort_t*)(ws + 16777216);
    ushort_t* Wtb   = (ushort_t*)(ws + 25165824);
    int*      flagp = (int*)(ws + 31457280);
    ushort_t* Xb    = (ushort_t*)d_out;

    k_cvt_x<<<1024, 256, 0, stream>>>(X, Xb, flagp);
    k_cvt_w<<<dim3(16, 16, 3), 256, 0, stream>>>(W, Wtb, flagp);
    k_qkv<<<dim3(24, 32), 256, 0, stream>>>(Xb, Wtb, Qb, Kb, Vtb);
    k_attn<<<dim3(16, 32), 512, 0, stream>>>(Qb, Kb, Vtb, mask, d_out, flagp);
}